// Round 3
// baseline (865.052 us; speedup 1.0000x reference)
//
#include <hip/hip_runtime.h>

#define NF 64
#define KEXP 50
#define TBL 4096
#define CUTF 5.0f
#define LOG2C 0.6931471805599453f
#define GRP 64            // nodes per group
#define NSUB 8            // sub-buckets per group (XCD heuristic)
#define CAP 256           // capacity per sub-bucket (mean 128, ~11 sigma)
#define OFLOW_MAX (1 << 17)

__device__ __forceinline__ float sspf(float x) {
    return fmaxf(x, 0.0f) + log1pf(expf(-fabsf(x))) - LOG2C;
}

__device__ __forceinline__ float bcast(float v, int k) {
    return __int_as_float(__builtin_amdgcn_readlane(__float_as_int(v), k));
}

// ---------------------------------------------------------------------------
// filt(d) lookup table: TBL x NF
// ---------------------------------------------------------------------------
__global__ void build_table_k(const float* __restrict__ f_w1, const float* __restrict__ f_b1,
                              const float* __restrict__ f_w2, const float* __restrict__ f_b2,
                              float* __restrict__ table) {
    __shared__ float rbf_s[KEXP];
    __shared__ float s_s[NF];
    const int t = blockIdx.x;
    const int f = threadIdx.x; // 0..63
    const float d = (float)t * (CUTF / (float)(TBL - 1));
    const float delta = CUTF / (float)(KEXP - 1);
    const float coeff = -0.5f / (delta * delta);
    if (f < KEXP) {
        float dd = d - (float)f * delta;
        rbf_s[f] = expf(coeff * dd * dd);
    }
    __syncthreads();
    float t1 = f_b1[f];
    for (int k = 0; k < KEXP; ++k) t1 = fmaf(rbf_s[k], f_w1[f * KEXP + k], t1);
    s_s[f] = sspf(t1);
    __syncthreads();
    float t2 = f_b2[f];
    for (int k = 0; k < NF; ++k) t2 = fmaf(s_s[k], f_w2[f * NF + k], t2);
    table[t * NF + f] = t2;
}

// ---------------------------------------------------------------------------
// prep: h = x @ lin_w.T + lin_b  (wave/node, weights in VGPR, readlane bcast)
// ---------------------------------------------------------------------------
__global__ void __launch_bounds__(256) prep_k(
    const float* __restrict__ x, const float* __restrict__ w, const float* __restrict__ b,
    float* __restrict__ h, int n_nodes)
{
    const int tid = threadIdx.x;
    const int lane = tid & 63;
    float wreg[NF];
    #pragma unroll
    for (int k = 0; k < NF; k += 4) {
        float4 q = *(const float4*)(w + (size_t)lane * NF + k);
        wreg[k] = q.x; wreg[k + 1] = q.y; wreg[k + 2] = q.z; wreg[k + 3] = q.w;
    }
    const float bias = b[lane];
    const int nwaves = (gridDim.x * blockDim.x) >> 6;
    const int gw = (blockIdx.x * blockDim.x + tid) >> 6;
    for (int n = gw; n < n_nodes; n += nwaves) {
        const float xv = x[(size_t)n * NF + lane];
        float a0 = bias, a1 = 0.f, a2 = 0.f, a3 = 0.f;
        #pragma unroll
        for (int k = 0; k < NF; k += 4) {
            a0 = fmaf(bcast(xv, k),     wreg[k],     a0);
            a1 = fmaf(bcast(xv, k + 1), wreg[k + 1], a1);
            a2 = fmaf(bcast(xv, k + 2), wreg[k + 2], a2);
            a3 = fmaf(bcast(xv, k + 3), wreg[k + 3], a3);
        }
        h[(size_t)n * NF + lane] = (a0 + a1) + (a2 + a3);
    }
}

// ---------------------------------------------------------------------------
// scatter: bin edge ids into (group, sub-bucket) regions. 4B records.
// rec = e | (dst_in_group << 21)
// ---------------------------------------------------------------------------
__global__ void __launch_bounds__(256) scatter_k(const int* __restrict__ nbr_dst,
                                                 unsigned* __restrict__ gcur,
                                                 unsigned* __restrict__ payload,
                                                 unsigned* __restrict__ oflow_cnt,
                                                 unsigned* __restrict__ oflow, int n_edges) {
    const unsigned sub = blockIdx.x & (NSUB - 1);
    const int gt = blockIdx.x * blockDim.x + threadIdx.x;
    const int gs = gridDim.x * blockDim.x;
    for (int e = gt; e < n_edges; e += gs) {
        const unsigned dst = (unsigned)nbr_dst[e];
        const unsigned g = dst >> 6;
        const unsigned dstin = dst & 63u;
        const unsigned slot = g * NSUB + sub;
        const unsigned pos = atomicAdd(&gcur[slot], 1u);
        if (pos < CAP) {
            payload[(size_t)slot * CAP + pos] = (unsigned)e | (dstin << 21);
        } else {
            const unsigned oi = atomicAdd(oflow_cnt, 1u);
            if (oi < OFLOW_MAX) oflow[oi] = (unsigned)e;
        }
    }
}

// ---------------------------------------------------------------------------
// aggregate: block = 64-node group; LDS tile accumulate; one coalesced write.
// ---------------------------------------------------------------------------
__global__ void __launch_bounds__(256) agg_k(const unsigned* __restrict__ gcur,
                                             const unsigned* __restrict__ payload,
                                             const int* __restrict__ nbr_src,
                                             const float* __restrict__ dist,
                                             const float* __restrict__ h,
                                             const float* __restrict__ table,
                                             float* __restrict__ agg, int n_nodes) {
    __shared__ float s[GRP][NF];
    const int tid = threadIdx.x;
    const int lane = tid & 63;
    const int wid = tid >> 6; // 0..3
    const int g = blockIdx.x;
    for (int i = tid; i < GRP * NF; i += 256) ((float*)s)[i] = 0.f;
    __syncthreads();
    const float scale = (float)(TBL - 1) / CUTF;
    for (int sub = wid; sub < NSUB; sub += 4) {
        const unsigned slot = (unsigned)g * NSUB + sub;
        const unsigned cnt = min(gcur[slot], (unsigned)CAP);
        const size_t base0 = (size_t)slot * CAP;
        for (unsigned b = 0; b < cnt; b += 64u) {
            const int m = (int)min(64u, cnt - b);
            unsigned w1 = 0u, w2 = 0u;
            if (lane < m) {
                const unsigned rec = payload[base0 + b + lane];
                const unsigned e = rec & 0x1FFFFFu;
                const unsigned dstin = rec >> 21;
                const unsigned sj = (unsigned)nbr_src[e];
                const float xx = dist[e] * scale;
                int i0 = (int)xx;
                i0 = max(0, min(i0, TBL - 2));
                const float fr = xx - (float)i0;
                const unsigned f16 = min((unsigned)(fr * 65536.0f), 65535u);
                w1 = sj | (dstin << 20);                 // sj < 2^20
                w2 = ((unsigned)i0 << 16) | f16;
            }
            #pragma unroll 4
            for (int j = 0; j < m; ++j) {
                const unsigned a  = (unsigned)__shfl((int)w1, j);
                const unsigned bq = (unsigned)__shfl((int)w2, j);
                const unsigned sj = a & 0xFFFFFu;
                const unsigned dstin = a >> 20;
                const int ij = (int)(bq >> 16);
                const float fj = (float)(bq & 0xFFFFu) * (1.0f / 65536.0f);
                const float t0 = table[(size_t)ij * NF + lane];
                const float t1 = table[(size_t)ij * NF + NF + lane];
                const float hv = h[(size_t)sj * NF + lane];
                const float filt = fmaf(fj, t1 - t0, t0);
                atomicAdd(&s[dstin][lane], hv * filt);
            }
        }
    }
    __syncthreads();
    const int n0 = g * GRP;
    for (int r = wid; r < GRP; r += 4) {
        const int n = n0 + r;
        if (n < n_nodes) agg[(size_t)n * NF + lane] = s[r][lane];
    }
}

// ---------------------------------------------------------------------------
// overflow fixup: global atomic adds for the (normally zero) overflow edges
// ---------------------------------------------------------------------------
__global__ void __launch_bounds__(256) oflow_fix_k(const unsigned* __restrict__ oflow_cnt,
                                                   const unsigned* __restrict__ oflow,
                                                   const int* __restrict__ nbr,
                                                   const float* __restrict__ dist,
                                                   const float* __restrict__ h,
                                                   const float* __restrict__ table,
                                                   float* __restrict__ agg, int n_edges) {
    const unsigned cnt = min(*oflow_cnt, (unsigned)OFLOW_MAX);
    const int lane = threadIdx.x & 63;
    const int gw = (blockIdx.x * blockDim.x + threadIdx.x) >> 6;
    const int nw = (gridDim.x * blockDim.x) >> 6;
    const float scale = (float)(TBL - 1) / CUTF;
    for (unsigned t = gw; t < cnt; t += nw) {
        const unsigned e = oflow[t];
        const int sj = nbr[e];
        const int dj = nbr[n_edges + e];
        const float xx = dist[e] * scale;
        int i0 = (int)xx;
        i0 = max(0, min(i0, TBL - 2));
        const float fr = xx - (float)i0;
        const float t0 = table[(size_t)i0 * NF + lane];
        const float t1 = table[(size_t)i0 * NF + NF + lane];
        const float filt = fmaf(fr, t1 - t0, t0);
        const float hv = h[(size_t)sj * NF + lane];
        atomicAdd(agg + (size_t)dj * NF + lane, hv * filt);
    }
}

// ---------------------------------------------------------------------------
// fallback edge kernel (atomic scatter-add) — used only if ws too small
// ---------------------------------------------------------------------------
__global__ void edge_k(const int* __restrict__ nbr, const float* __restrict__ dist,
                       const float* __restrict__ h, const float* __restrict__ table,
                       float* __restrict__ agg, int n_edges) {
    const int tid = threadIdx.x;
    const int lane = tid & 63;
    const int nwaves = (gridDim.x * blockDim.x) >> 6;
    const int gw = (blockIdx.x * blockDim.x + tid) >> 6;
    const float scale = (float)(TBL - 1) / CUTF;
    const int nbatch = n_edges >> 6;
    for (int bb = gw; bb < nbatch; bb += nwaves) {
        const int e0 = bb << 6;
        int src = nbr[e0 + lane];
        int dst = nbr[n_edges + e0 + lane];
        float d = dist[e0 + lane];
        float xx = d * scale;
        int i0 = (int)xx;
        i0 = max(0, min(i0, TBL - 2));
        float frac = xx - (float)i0;
        #pragma unroll 4
        for (int j = 0; j < 64; ++j) {
            const int sj = __shfl(src, j);
            const int dj = __shfl(dst, j);
            const int ij = __shfl(i0, j);
            const float fj = __shfl(frac, j);
            const float t0 = table[ij * NF + lane];
            const float t1 = table[ij * NF + NF + lane];
            const float filt = fmaf(fj, t1 - t0, t0);
            const float hv = h[(size_t)sj * NF + lane];
            atomicAdd(agg + (size_t)dj * NF + lane, hv * filt);
        }
    }
    if (gw == 0) {
        for (int e = nbatch << 6; e < n_edges; ++e) {
            const int sj = nbr[e];
            const int dj = nbr[n_edges + e];
            const float d = dist[e];
            float xx = d * scale;
            int ij = (int)xx;
            ij = max(0, min(ij, TBL - 2));
            const float fj = xx - (float)ij;
            const float t0 = table[ij * NF + lane];
            const float t1 = table[ij * NF + NF + lane];
            const float filt = fmaf(fj, t1 - t0, t0);
            const float hv = h[(size_t)sj * NF + lane];
            atomicAdd(agg + (size_t)dj * NF + lane, hv * filt);
        }
    }
}

// ---------------------------------------------------------------------------
// out = ssp(agg @ m_w1.T + m_b1) @ m_w2.T + m_b2  (wave/node, weights in VGPR)
// safe in-place (agg may alias out; row-local)
// ---------------------------------------------------------------------------
__global__ void __launch_bounds__(256) out_mlp_k(const float* __restrict__ agg,
                                                 const float* __restrict__ w1,
                                                 const float* __restrict__ b1,
                                                 const float* __restrict__ w2,
                                                 const float* __restrict__ b2,
                                                 float* __restrict__ out, int n_nodes) {
    const int tid = threadIdx.x;
    const int lane = tid & 63;
    float w1reg[NF], w2reg[NF];
    #pragma unroll
    for (int k = 0; k < NF; k += 4) {
        float4 q1 = *(const float4*)(w1 + (size_t)lane * NF + k);
        w1reg[k] = q1.x; w1reg[k + 1] = q1.y; w1reg[k + 2] = q1.z; w1reg[k + 3] = q1.w;
        float4 q2 = *(const float4*)(w2 + (size_t)lane * NF + k);
        w2reg[k] = q2.x; w2reg[k + 1] = q2.y; w2reg[k + 2] = q2.z; w2reg[k + 3] = q2.w;
    }
    const float bias1 = b1[lane], bias2 = b2[lane];
    const int nwaves = (gridDim.x * blockDim.x) >> 6;
    const int gw = (blockIdx.x * blockDim.x + tid) >> 6;
    for (int n = gw; n < n_nodes; n += nwaves) {
        const float av = agg[(size_t)n * NF + lane];
        float a0 = bias1, a1 = 0.f, a2 = 0.f, a3 = 0.f;
        #pragma unroll
        for (int k = 0; k < NF; k += 4) {
            a0 = fmaf(bcast(av, k),     w1reg[k],     a0);
            a1 = fmaf(bcast(av, k + 1), w1reg[k + 1], a1);
            a2 = fmaf(bcast(av, k + 2), w1reg[k + 2], a2);
            a3 = fmaf(bcast(av, k + 3), w1reg[k + 3], a3);
        }
        const float s = sspf((a0 + a1) + (a2 + a3));
        float o0 = bias2, o1 = 0.f, o2 = 0.f, o3 = 0.f;
        #pragma unroll
        for (int k = 0; k < NF; k += 4) {
            o0 = fmaf(bcast(s, k),     w2reg[k],     o0);
            o1 = fmaf(bcast(s, k + 1), w2reg[k + 1], o1);
            o2 = fmaf(bcast(s, k + 2), w2reg[k + 2], o2);
            o3 = fmaf(bcast(s, k + 3), w2reg[k + 3], o3);
        }
        out[(size_t)n * NF + lane] = (o0 + o1) + (o2 + o3);
    }
}

extern "C" void kernel_launch(void* const* d_in, const int* in_sizes, int n_in,
                              void* d_out, int out_size, void* d_ws, size_t ws_size,
                              hipStream_t stream) {
    const int*   nbr   = (const int*)d_in[0];
    const float* dist  = (const float*)d_in[1];
    const float* x     = (const float*)d_in[2];
    const float* lin_w = (const float*)d_in[3];
    const float* lin_b = (const float*)d_in[4];
    const float* f_w1  = (const float*)d_in[5];
    const float* f_b1  = (const float*)d_in[6];
    const float* f_w2  = (const float*)d_in[7];
    const float* f_b2  = (const float*)d_in[8];
    const float* m_w1  = (const float*)d_in[9];
    const float* m_b1  = (const float*)d_in[10];
    const float* m_w2  = (const float*)d_in[11];
    const float* m_b2  = (const float*)d_in[12];

    const int n_edges = in_sizes[1];
    const int n_nodes = in_sizes[2] / NF;
    const int ngroups = (n_nodes + GRP - 1) / GRP;

    float* out = (float*)d_out;

    // workspace layout
    char* ws = (char*)d_ws;
    size_t off = 0;
    auto alloc = [&](size_t bytes) { char* p = ws + off; off = (off + bytes + 255) & ~(size_t)255; return p; };
    float*    h_ws      = (float*)alloc((size_t)n_nodes * NF * sizeof(float));
    float*    table     = (float*)alloc((size_t)TBL * NF * sizeof(float));
    unsigned* gcur      = (unsigned*)alloc((size_t)ngroups * NSUB * sizeof(unsigned));
    unsigned* oflow_cnt = (unsigned*)alloc(sizeof(unsigned));
    unsigned* oflow     = (unsigned*)alloc((size_t)OFLOW_MAX * sizeof(unsigned));
    unsigned* payload   = (unsigned*)alloc((size_t)ngroups * NSUB * CAP * sizeof(unsigned));
    const bool bucket_path = (off <= ws_size) && (n_edges <= (1 << 21)) && (n_nodes <= (1 << 20));

    build_table_k<<<TBL, 64, 0, stream>>>(f_w1, f_b1, f_w2, f_b2, table);

    if (bucket_path) {
        // zero cursors + overflow count (contiguous region)
        hipMemsetAsync(gcur, 0, (char*)(oflow_cnt + 1) - (char*)gcur, stream);
        prep_k<<<2048, 256, 0, stream>>>(x, lin_w, lin_b, h_ws, n_nodes);
        scatter_k<<<2048, 256, 0, stream>>>(nbr + n_edges, gcur, payload, oflow_cnt, oflow, n_edges);
        float* agg = out; // agg lives in d_out; out_mlp runs in place
        agg_k<<<ngroups, 256, 0, stream>>>(gcur, payload, nbr, dist, h_ws, table, agg, n_nodes);
        oflow_fix_k<<<32, 256, 0, stream>>>(oflow_cnt, oflow, nbr, dist, h_ws, table, agg, n_edges);
        out_mlp_k<<<1024, 256, 0, stream>>>(agg, m_w1, m_b1, m_w2, m_b2, out, n_nodes);
    } else {
        // fallback: atomic scatter-add path (h in d_out, agg in ws)
        float* h   = out;
        float* agg = h_ws; // reuse first ws region
        hipMemsetAsync(agg, 0, (size_t)n_nodes * NF * sizeof(float), stream);
        prep_k<<<2048, 256, 0, stream>>>(x, lin_w, lin_b, h, n_nodes);
        edge_k<<<2048, 256, 0, stream>>>(nbr, dist, h, table, agg, n_edges);
        out_mlp_k<<<1024, 256, 0, stream>>>(agg, m_w1, m_b1, m_w2, m_b2, out, n_nodes);
    }
}

// Round 4
// 850.358 us; speedup vs baseline: 1.0173x; 1.0173x over previous
//
#include <hip/hip_runtime.h>

#define NF 64
#define KEXP 50
#define TBL 4096
#define CUTF 5.0f
#define LOG2C 0.6931471805599453f
#define GRP 64            // nodes per group
#define NSUB 8            // sub-buckets per group (XCD heuristic via blockIdx&7)
#define OFLOW_MAX (1 << 18)
#define MIN_CAP 112

__device__ __forceinline__ float sspf(float x) {
    return fmaxf(x, 0.0f) + log1pf(expf(-fabsf(x))) - LOG2C;
}

__device__ __forceinline__ float bcast(float v, int k) {
    return __int_as_float(__builtin_amdgcn_readlane(__float_as_int(v), k));
}

// ---------------------------------------------------------------------------
// interleaved lerp table: tab2[t][lane] = (filt_t[lane], filt_{t+1}[lane])
// ---------------------------------------------------------------------------
__global__ void build_tab2_k(const float* __restrict__ f_w1, const float* __restrict__ f_b1,
                             const float* __restrict__ f_w2, const float* __restrict__ f_b2,
                             float2* __restrict__ tab2) {
    __shared__ float rbf_s[KEXP];
    __shared__ float s_s[NF];
    const int t = blockIdx.x;
    const int f = threadIdx.x; // 0..63
    const float d = (float)t * (CUTF / (float)(TBL - 1));
    const float delta = CUTF / (float)(KEXP - 1);
    const float coeff = -0.5f / (delta * delta);
    if (f < KEXP) {
        float dd = d - (float)f * delta;
        rbf_s[f] = expf(coeff * dd * dd);
    }
    __syncthreads();
    float t1 = f_b1[f];
    for (int k = 0; k < KEXP; ++k) t1 = fmaf(rbf_s[k], f_w1[f * KEXP + k], t1);
    s_s[f] = sspf(t1);
    __syncthreads();
    float t2 = f_b2[f];
    for (int k = 0; k < NF; ++k) t2 = fmaf(s_s[k], f_w2[f * NF + k], t2);
    // row t is the .x of entry t and the .y of entry t-1
    if (t < TBL - 1) tab2[(size_t)t * NF + f].x = t2;
    if (t > 0)       tab2[(size_t)(t - 1) * NF + f].y = t2;
}

// ---------------------------------------------------------------------------
// prep: h = x @ lin_w.T + lin_b  (wave/node, weights in VGPR, readlane bcast)
// ---------------------------------------------------------------------------
__global__ void __launch_bounds__(256) prep_k(
    const float* __restrict__ x, const float* __restrict__ w, const float* __restrict__ b,
    float* __restrict__ h, int n_nodes)
{
    const int tid = threadIdx.x;
    const int lane = tid & 63;
    float wreg[NF];
    #pragma unroll
    for (int k = 0; k < NF; k += 4) {
        float4 q = *(const float4*)(w + (size_t)lane * NF + k);
        wreg[k] = q.x; wreg[k + 1] = q.y; wreg[k + 2] = q.z; wreg[k + 3] = q.w;
    }
    const float bias = b[lane];
    const int nwaves = (gridDim.x * blockDim.x) >> 6;
    const int gw = (blockIdx.x * blockDim.x + tid) >> 6;
    for (int n = gw; n < n_nodes; n += nwaves) {
        const float xv = x[(size_t)n * NF + lane];
        float a0 = bias, a1 = 0.f, a2 = 0.f, a3 = 0.f;
        #pragma unroll
        for (int k = 0; k < NF; k += 4) {
            a0 = fmaf(bcast(xv, k),     wreg[k],     a0);
            a1 = fmaf(bcast(xv, k + 1), wreg[k + 1], a1);
            a2 = fmaf(bcast(xv, k + 2), wreg[k + 2], a2);
            a3 = fmaf(bcast(xv, k + 3), wreg[k + 3], a3);
        }
        h[(size_t)n * NF + lane] = (a0 + a1) + (a2 + a3);
    }
}

// ---------------------------------------------------------------------------
// scatter: full 8B records into (group, sub-bucket) regions.
// rec = (src | dstin<<20, i0<<16 | frac16)
// ---------------------------------------------------------------------------
__global__ void __launch_bounds__(256) scatter_k(const int* __restrict__ nbr,
                                                 const float* __restrict__ dist,
                                                 unsigned* __restrict__ gcur,
                                                 uint2* __restrict__ payload, int cap,
                                                 unsigned* __restrict__ oflow_cnt,
                                                 unsigned* __restrict__ oflow, int n_edges) {
    const unsigned sub = blockIdx.x & (NSUB - 1);
    const float scale = (float)(TBL - 1) / CUTF;
    const int gt = blockIdx.x * blockDim.x + threadIdx.x;
    const int gs = gridDim.x * blockDim.x;
    for (int e = gt; e < n_edges; e += gs) {
        const unsigned dst = (unsigned)nbr[n_edges + e];
        const unsigned src = (unsigned)nbr[e];
        const float xx = dist[e] * scale;
        int i0 = (int)xx;
        i0 = max(0, min(i0, TBL - 2));
        const float fr = xx - (float)i0;
        const unsigned f16 = min((unsigned)(fr * 65536.0f), 65535u);
        const unsigned slot = (dst >> 6) * NSUB + sub;
        const unsigned pos = atomicAdd(&gcur[slot], 1u);
        if ((int)pos < cap) {
            payload[(size_t)slot * cap + pos] =
                make_uint2(src | ((dst & 63u) << 20), ((unsigned)i0 << 16) | f16);
        } else {
            const unsigned oi = atomicAdd(oflow_cnt, 1u);
            if (oi < OFLOW_MAX) oflow[oi] = (unsigned)e;
        }
    }
}

// ---------------------------------------------------------------------------
// aggregate: block = 64-node group; LDS tile; coalesced payload; no gathers.
// ---------------------------------------------------------------------------
__global__ void __launch_bounds__(256) agg_k(const unsigned* __restrict__ gcur,
                                             const uint2* __restrict__ payload, int cap,
                                             const float* __restrict__ h,
                                             const float2* __restrict__ tab2,
                                             float* __restrict__ agg, int n_nodes) {
    __shared__ float s[GRP][NF];
    const int tid = threadIdx.x;
    const int lane = tid & 63;
    const int wid = tid >> 6; // 0..3
    const int g = blockIdx.x;
    for (int i = tid; i < GRP * NF; i += 256) ((float*)s)[i] = 0.f;
    __syncthreads();

    auto edge = [&](unsigned a, unsigned q) {
        const unsigned sj = a & 0xFFFFFu;
        const unsigned dstin = a >> 20;
        const int ij = (int)(q >> 16);
        const float fj = (float)(q & 0xFFFFu) * (1.0f / 65536.0f);
        const float2 t = tab2[(size_t)ij * NF + lane];
        const float hv = h[(size_t)sj * NF + lane];
        const float filt = fmaf(fj, t.y - t.x, t.x);
        atomicAdd(&s[dstin][lane], hv * filt);
    };

    for (int sub = wid; sub < NSUB; sub += 4) {
        const unsigned slot = (unsigned)g * NSUB + sub;
        const unsigned cnt = min(gcur[slot], (unsigned)cap);
        const uint2* pp = payload + (size_t)slot * cap;
        unsigned b = 0;
        for (; b + 64u <= cnt; b += 64u) {
            const uint2 pl = pp[b + lane];
            #pragma unroll
            for (int j0 = 0; j0 < 64; j0 += 8) {
                #pragma unroll
                for (int j = 0; j < 8; ++j) {
                    const unsigned a = (unsigned)__shfl((int)pl.x, j0 + j);
                    const unsigned q = (unsigned)__shfl((int)pl.y, j0 + j);
                    edge(a, q);
                }
            }
        }
        const int m = (int)(cnt - b);
        if (m > 0) {
            uint2 pl = make_uint2(0u, 0u);
            if (lane < m) pl = pp[b + lane];
            for (int j = 0; j < m; ++j) {
                const unsigned a = (unsigned)__shfl((int)pl.x, j);
                const unsigned q = (unsigned)__shfl((int)pl.y, j);
                edge(a, q);
            }
        }
    }
    __syncthreads();
    const int n0 = g * GRP;
    for (int r = wid; r < GRP; r += 4) {
        const int n = n0 + r;
        if (n < n_nodes) agg[(size_t)n * NF + lane] = s[r][lane];
    }
}

// ---------------------------------------------------------------------------
// overflow fixup: global atomic adds (normally ~0 edges)
// ---------------------------------------------------------------------------
__global__ void __launch_bounds__(256) oflow_fix_k(const unsigned* __restrict__ oflow_cnt,
                                                   const unsigned* __restrict__ oflow,
                                                   const int* __restrict__ nbr,
                                                   const float* __restrict__ dist,
                                                   const float* __restrict__ h,
                                                   const float2* __restrict__ tab2,
                                                   float* __restrict__ agg, int n_edges) {
    const unsigned cnt = min(*oflow_cnt, (unsigned)OFLOW_MAX);
    const int lane = threadIdx.x & 63;
    const int gw = (blockIdx.x * blockDim.x + threadIdx.x) >> 6;
    const int nw = (gridDim.x * blockDim.x) >> 6;
    const float scale = (float)(TBL - 1) / CUTF;
    for (unsigned t = gw; t < cnt; t += nw) {
        const unsigned e = oflow[t];
        const int sj = nbr[e];
        const int dj = nbr[n_edges + e];
        const float xx = dist[e] * scale;
        int i0 = (int)xx;
        i0 = max(0, min(i0, TBL - 2));
        const float fr = xx - (float)i0;
        const float2 tv = tab2[(size_t)i0 * NF + lane];
        const float filt = fmaf(fr, tv.y - tv.x, tv.x);
        const float hv = h[(size_t)sj * NF + lane];
        atomicAdd(agg + (size_t)dj * NF + lane, hv * filt);
    }
}

// ---------------------------------------------------------------------------
// fallback edge kernel (atomic scatter-add) — used only if ws too small
// ---------------------------------------------------------------------------
__global__ void edge_k(const int* __restrict__ nbr, const float* __restrict__ dist,
                       const float* __restrict__ h, const float2* __restrict__ tab2,
                       float* __restrict__ agg, int n_edges) {
    const int tid = threadIdx.x;
    const int lane = tid & 63;
    const int nwaves = (gridDim.x * blockDim.x) >> 6;
    const int gw = (blockIdx.x * blockDim.x + tid) >> 6;
    const float scale = (float)(TBL - 1) / CUTF;
    const int nbatch = n_edges >> 6;
    for (int bb = gw; bb < nbatch; bb += nwaves) {
        const int e0 = bb << 6;
        int src = nbr[e0 + lane];
        int dst = nbr[n_edges + e0 + lane];
        float d = dist[e0 + lane];
        float xx = d * scale;
        int i0 = (int)xx;
        i0 = max(0, min(i0, TBL - 2));
        float frac = xx - (float)i0;
        #pragma unroll 4
        for (int j = 0; j < 64; ++j) {
            const int sj = __shfl(src, j);
            const int dj = __shfl(dst, j);
            const int ij = __shfl(i0, j);
            const float fj = __shfl(frac, j);
            const float2 tv = tab2[(size_t)ij * NF + lane];
            const float filt = fmaf(fj, tv.y - tv.x, tv.x);
            const float hv = h[(size_t)sj * NF + lane];
            atomicAdd(agg + (size_t)dj * NF + lane, hv * filt);
        }
    }
    if (gw == 0) {
        for (int e = nbatch << 6; e < n_edges; ++e) {
            const int sj = nbr[e];
            const int dj = nbr[n_edges + e];
            const float d = dist[e];
            float xx = d * scale;
            int ij = (int)xx;
            ij = max(0, min(ij, TBL - 2));
            const float fj = xx - (float)ij;
            const float2 tv = tab2[(size_t)ij * NF + lane];
            const float filt = fmaf(fj, tv.y - tv.x, tv.x);
            const float hv = h[(size_t)sj * NF + lane];
            atomicAdd(agg + (size_t)dj * NF + lane, hv * filt);
        }
    }
}

// ---------------------------------------------------------------------------
// out = ssp(agg @ m_w1.T + m_b1) @ m_w2.T + m_b2  (wave/node, weights in VGPR)
// ---------------------------------------------------------------------------
__global__ void __launch_bounds__(256) out_mlp_k(const float* __restrict__ agg,
                                                 const float* __restrict__ w1,
                                                 const float* __restrict__ b1,
                                                 const float* __restrict__ w2,
                                                 const float* __restrict__ b2,
                                                 float* __restrict__ out, int n_nodes) {
    const int tid = threadIdx.x;
    const int lane = tid & 63;
    float w1reg[NF], w2reg[NF];
    #pragma unroll
    for (int k = 0; k < NF; k += 4) {
        float4 q1 = *(const float4*)(w1 + (size_t)lane * NF + k);
        w1reg[k] = q1.x; w1reg[k + 1] = q1.y; w1reg[k + 2] = q1.z; w1reg[k + 3] = q1.w;
        float4 q2 = *(const float4*)(w2 + (size_t)lane * NF + k);
        w2reg[k] = q2.x; w2reg[k + 1] = q2.y; w2reg[k + 2] = q2.z; w2reg[k + 3] = q2.w;
    }
    const float bias1 = b1[lane], bias2 = b2[lane];
    const int nwaves = (gridDim.x * blockDim.x) >> 6;
    const int gw = (blockIdx.x * blockDim.x + tid) >> 6;
    for (int n = gw; n < n_nodes; n += nwaves) {
        const float av = agg[(size_t)n * NF + lane];
        float a0 = bias1, a1 = 0.f, a2 = 0.f, a3 = 0.f;
        #pragma unroll
        for (int k = 0; k < NF; k += 4) {
            a0 = fmaf(bcast(av, k),     w1reg[k],     a0);
            a1 = fmaf(bcast(av, k + 1), w1reg[k + 1], a1);
            a2 = fmaf(bcast(av, k + 2), w1reg[k + 2], a2);
            a3 = fmaf(bcast(av, k + 3), w1reg[k + 3], a3);
        }
        const float s = sspf((a0 + a1) + (a2 + a3));
        float o0 = bias2, o1 = 0.f, o2 = 0.f, o3 = 0.f;
        #pragma unroll
        for (int k = 0; k < NF; k += 4) {
            o0 = fmaf(bcast(s, k),     w2reg[k],     o0);
            o1 = fmaf(bcast(s, k + 1), w2reg[k + 1], o1);
            o2 = fmaf(bcast(s, k + 2), w2reg[k + 2], o2);
            o3 = fmaf(bcast(s, k + 3), w2reg[k + 3], o3);
        }
        out[(size_t)n * NF + lane] = (o0 + o1) + (o2 + o3);
    }
}

extern "C" void kernel_launch(void* const* d_in, const int* in_sizes, int n_in,
                              void* d_out, int out_size, void* d_ws, size_t ws_size,
                              hipStream_t stream) {
    const int*   nbr   = (const int*)d_in[0];
    const float* dist  = (const float*)d_in[1];
    const float* x     = (const float*)d_in[2];
    const float* lin_w = (const float*)d_in[3];
    const float* lin_b = (const float*)d_in[4];
    const float* f_w1  = (const float*)d_in[5];
    const float* f_b1  = (const float*)d_in[6];
    const float* f_w2  = (const float*)d_in[7];
    const float* f_b2  = (const float*)d_in[8];
    const float* m_w1  = (const float*)d_in[9];
    const float* m_b1  = (const float*)d_in[10];
    const float* m_w2  = (const float*)d_in[11];
    const float* m_b2  = (const float*)d_in[12];

    const int n_edges = in_sizes[1];
    const int n_nodes = in_sizes[2] / NF;
    const int ngroups = (n_nodes + GRP - 1) / GRP;

    float* out = (float*)d_out;
    float* h   = out;  // h lives in d_out (dead once agg/oflow done; out_mlp overwrites)

    // workspace layout: agg | tab2 | gcur | oflow_cnt | oflow | payload(rest)
    char* ws = (char*)d_ws;
    size_t off = 0;
    auto alloc = [&](size_t bytes) { char* p = ws + off; off = (off + bytes + 255) & ~(size_t)255; return p; };
    float*    agg       = (float*)alloc((size_t)n_nodes * NF * sizeof(float));
    float2*   tab2      = (float2*)alloc((size_t)TBL * NF * sizeof(float2));
    unsigned* gcur      = (unsigned*)alloc((size_t)ngroups * NSUB * sizeof(unsigned));
    unsigned* oflow_cnt = (unsigned*)alloc(sizeof(unsigned));
    unsigned* oflow     = (unsigned*)alloc((size_t)OFLOW_MAX * sizeof(unsigned));
    uint2*    payload   = (uint2*)(ws + off);

    long long avail = (long long)ws_size - (long long)off;
    long long cap_ll = 0;
    if (avail > 0) cap_ll = avail / ((long long)ngroups * NSUB * (long long)sizeof(uint2));
    const int cap = (int)(cap_ll > 256 ? 256 : cap_ll);
    const bool bucket_path = (cap >= MIN_CAP) && (n_edges <= (1 << 21)) && (n_nodes <= (1 << 20));

    build_tab2_k<<<TBL, 64, 0, stream>>>(f_w1, f_b1, f_w2, f_b2, tab2);

    if (bucket_path) {
        hipMemsetAsync(gcur, 0, (char*)(oflow_cnt + 1) - (char*)gcur, stream);
        prep_k<<<2048, 256, 0, stream>>>(x, lin_w, lin_b, h, n_nodes);
        scatter_k<<<2048, 256, 0, stream>>>(nbr, dist, gcur, payload, cap,
                                            oflow_cnt, oflow, n_edges);
        agg_k<<<ngroups, 256, 0, stream>>>(gcur, payload, cap, h, tab2, agg, n_nodes);
        oflow_fix_k<<<64, 256, 0, stream>>>(oflow_cnt, oflow, nbr, dist, h, tab2, agg, n_edges);
        out_mlp_k<<<1024, 256, 0, stream>>>(agg, m_w1, m_b1, m_w2, m_b2, out, n_nodes);
    } else {
        // fallback: atomic scatter-add path (h in d_out, agg in ws)
        hipMemsetAsync(agg, 0, (size_t)n_nodes * NF * sizeof(float), stream);
        prep_k<<<2048, 256, 0, stream>>>(x, lin_w, lin_b, h, n_nodes);
        edge_k<<<2048, 256, 0, stream>>>(nbr, dist, h, tab2, agg, n_edges);
        out_mlp_k<<<1024, 256, 0, stream>>>(agg, m_w1, m_b1, m_w2, m_b2, out, n_nodes);
    }
}